// Round 2
// baseline (1338.410 us; speedup 1.0000x reference)
//
#include <hip/hip_runtime.h>
#include <hip/hip_bf16.h>
#include <math.h>

typedef __attribute__((ext_vector_type(8))) short short8;
typedef __attribute__((ext_vector_type(4))) float floatx4;
typedef unsigned short u16;

__device__ __forceinline__ float bf2f(u16 h) {
  union { unsigned u; float f; } v; v.u = ((unsigned)h) << 16; return v.f;
}
__device__ __forceinline__ u16 f2bf(float f) {
  union { float f; unsigned u; } v; v.f = f;
  unsigned r = v.u + 0x7FFFu + ((v.u >> 16) & 1u);
  return (u16)(r >> 16);
}

// dtype-adaptive loads: flag=1 -> underlying fp32, flag=0 -> underlying bf16
__device__ __forceinline__ float ldf_dyn(const void* p, size_t i, bool f32) {
  return f32 ? ((const float*)p)[i] : bf2f(((const u16*)p)[i]);
}
__device__ __forceinline__ short8 load8_dyn(const void* p, size_t idx, bool f32) {
  if (f32) {
    const float* f = (const float*)p;
    float4 a = *(const float4*)(f + idx);
    float4 b = *(const float4*)(f + idx + 4);
    short8 r;
    r[0] = (short)f2bf(a.x); r[1] = (short)f2bf(a.y);
    r[2] = (short)f2bf(a.z); r[3] = (short)f2bf(a.w);
    r[4] = (short)f2bf(b.x); r[5] = (short)f2bf(b.y);
    r[6] = (short)f2bf(b.z); r[7] = (short)f2bf(b.w);
    return r;
  }
  return *(const short8*)((const u16*)p + idx);
}

// ---------------------------------------------------------------------------
// Probe: decide whether inputs are fp32 or bf16 by exponent statistics of the
// first 8192 u16 halves of hidden_states. bf16 N(0,1): ~100% plausible.
// fp32 N(0,1): even halves are mantissa bits -> ~38% plausible -> total ~69%.
// ---------------------------------------------------------------------------
__global__ void probe_dtype_kernel(const void* hidden, int* flag) {
  __shared__ int cnt;
  if (threadIdx.x == 0) cnt = 0;
  __syncthreads();
  const u16* h = (const u16*)hidden;
  int local = 0;
  for (int i = threadIdx.x; i < 8192; i += 256) {
    u16 u = h[i];
    int e = (u >> 7) & 0xFF;
    if ((e >= 64 && e <= 160) || (u & 0x7FFF) == 0) local++;
  }
  atomicAdd(&cnt, local);
  __syncthreads();
  if (threadIdx.x == 0) *flag = (cnt < 7700) ? 1 : 0;  // 1 = fp32 inputs
}

// ---------------------------------------------------------------------------
// GEMM: C[M,N] = A[M,K] * B[K,N] row-major, fp32 accumulate, bf16 MFMA.
// A/B/C dtype selected by (adyn/bdyn/cdyn && *flagp): dyn=1 means "harness
// dtype" (fp32 or bf16 per flag), dyn=0 means internal bf16 buffer.
// 128x128 tile, BK=32, 256 threads, 4x4 MFMA tiles per wave.
// ---------------------------------------------------------------------------
__global__ __launch_bounds__(256) void gemm_dyn_kernel(
    const void* __restrict__ A, const void* __restrict__ B, void* __restrict__ C,
    int M, int N, int K, const int* __restrict__ flagp,
    int adyn, int bdyn, int cdyn)
{
  __shared__ __attribute__((aligned(16))) u16 As[128 * 40];
  __shared__ __attribute__((aligned(16))) u16 Bs[128 * 40];
  const bool f32 = (*flagp != 0);
  const bool af32 = adyn && f32, bf32 = bdyn && f32, cf32 = cdyn && f32;
  const int tid = threadIdx.x;
  const int wave = tid >> 6, lane = tid & 63;
  const int lane15 = lane & 15, quad = lane >> 4;
  const int wr = (wave >> 1) * 64, wc = (wave & 1) * 64;
  const int m0 = blockIdx.y * 128, n0 = blockIdx.x * 128;

  floatx4 zero = {0.0f, 0.0f, 0.0f, 0.0f};
  floatx4 acc[4][4];
#pragma unroll
  for (int i = 0; i < 4; i++)
#pragma unroll
    for (int j = 0; j < 4; j++) acc[i][j] = zero;

  for (int k0 = 0; k0 < K; k0 += 32) {
#pragma unroll
    for (int i = 0; i < 2; i++) {
      int c = tid + i * 256;
      int row = c >> 2, kc = (c & 3) << 3;
      short8 v = load8_dyn(A, (size_t)(m0 + row) * K + (k0 + kc), af32);
      *(short8*)(&As[row * 40 + kc]) = v;
    }
#pragma unroll
    for (int i = 0; i < 2; i++) {
      int c = tid + i * 256;
      int row = c >> 4, nc = (c & 15) << 3;
      short8 v = load8_dyn(B, (size_t)(k0 + row) * N + (n0 + nc), bf32);
      const u16* e = (const u16*)&v;
#pragma unroll
      for (int j = 0; j < 8; j++) Bs[(nc + j) * 40 + row] = e[j];
    }
    __syncthreads();
    short8 af[4], bfr[4];
#pragma unroll
    for (int mi = 0; mi < 4; mi++)
      af[mi] = *(const short8*)(&As[(wr + mi * 16 + lane15) * 40 + quad * 8]);
#pragma unroll
    for (int ni = 0; ni < 4; ni++)
      bfr[ni] = *(const short8*)(&Bs[(wc + ni * 16 + lane15) * 40 + quad * 8]);
#pragma unroll
    for (int mi = 0; mi < 4; mi++)
#pragma unroll
      for (int ni = 0; ni < 4; ni++)
        acc[mi][ni] = __builtin_amdgcn_mfma_f32_16x16x32_bf16(
            af[mi], bfr[ni], acc[mi][ni], 0, 0, 0);
    __syncthreads();
  }
  // C/D layout: col=lane&15, row=quad*4+r (m89-verified)
  if (cf32) {
    float* Cf = (float*)C;
#pragma unroll
    for (int mi = 0; mi < 4; mi++)
#pragma unroll
      for (int r = 0; r < 4; r++) {
        int m = m0 + wr + mi * 16 + quad * 4 + r;
        float* crow = Cf + (size_t)m * N + n0 + wc;
#pragma unroll
        for (int ni = 0; ni < 4; ni++) crow[ni * 16 + lane15] = acc[mi][ni][r];
      }
  } else {
    u16* Cb = (u16*)C;
#pragma unroll
    for (int mi = 0; mi < 4; mi++)
#pragma unroll
      for (int r = 0; r < 4; r++) {
        int m = m0 + wr + mi * 16 + quad * 4 + r;
        u16* crow = Cb + (size_t)m * N + n0 + wc;
#pragma unroll
        for (int ni = 0; ni < 4; ni++) crow[ni * 16 + lane15] = f2bf(acc[mi][ni][r]);
      }
  }
}

// ---------------------------------------------------------------------------
// RMS-norm + RoPE in place on q (16 heads) and k (8 heads) of internal qkv.
// grid (S, 24), block 256.
// ---------------------------------------------------------------------------
__global__ __launch_bounds__(256) void normrope_kernel(
    u16* __restrict__ qkv, const void* __restrict__ qw,
    const void* __restrict__ kw, const void* __restrict__ cosb,
    const void* __restrict__ sinb, const int* __restrict__ flagp)
{
  const bool f32 = (*flagp != 0);
  const int s = blockIdx.x;
  const int hh = blockIdx.y;
  const int d = threadIdx.x;
  const int col = (hh < 16) ? hh * 256 : 4096 + (hh - 16) * 256;
  const void* w = (hh < 16) ? qw : kw;
  u16* row = qkv + (size_t)s * 8192 + col;

  float x = bf2f(row[d]);
  int pd = (d < 128) ? d + 128 : d - 128;
  float xp = bf2f(row[pd]);

  float ss = x * x;
#pragma unroll
  for (int off = 32; off > 0; off >>= 1) ss += __shfl_xor(ss, off);
  __shared__ float red[4];
  if ((threadIdx.x & 63) == 0) red[threadIdx.x >> 6] = ss;
  __syncthreads();
  float tot = red[0] + red[1] + red[2] + red[3];
  float inv = rsqrtf(tot * (1.0f / 256.0f) + 1e-6f);

  float g = 1.0f + ldf_dyn(w, d, f32);
  float gp = 1.0f + ldf_dyn(w, pd, f32);
  float y = x * inv * g;
  float yp = xp * inv * gp;
  float rot = (d < 128) ? -yp : yp;
  float c = ldf_dyn(cosb, (size_t)s * 256 + d, f32);
  float sn = ldf_dyn(sinb, (size_t)s * 256 + d, f32);
  float outv = y * c + rot * sn;
  __syncthreads();  // all reads done before in-place writes
  row[d] = f2bf(outv);
}

// ---------------------------------------------------------------------------
// V transpose: vT[kv][d][s] = qkv[s][6144 + kv*256 + d]. grid (32,4,8).
// ---------------------------------------------------------------------------
__global__ __launch_bounds__(256) void vtrans_kernel(
    const u16* __restrict__ qkv, u16* __restrict__ vT)
{
  const int s0 = blockIdx.x * 64, d0 = blockIdx.y * 64, kv = blockIdx.z;
  __shared__ __attribute__((aligned(16))) u16 T[64][72];
  const int tid = threadIdx.x;
#pragma unroll
  for (int i = 0; i < 2; i++) {
    int c = tid + i * 256;
    int r = c >> 3, dc = (c & 7) << 3;
    *(short8*)(&T[r][dc]) =
        *(const short8*)(qkv + (size_t)(s0 + r) * 8192 + 6144 + kv * 256 + d0 + dc);
  }
  __syncthreads();
#pragma unroll
  for (int i = 0; i < 2; i++) {
    int c = tid + i * 256;
    int dr = c >> 3, sc = (c & 7) << 3;
    __attribute__((aligned(16))) u16 tmp[8];
#pragma unroll
    for (int j = 0; j < 8; j++) tmp[j] = T[sc + j][dr];
    *(short8*)(vT + (size_t)kv * 524288 + (size_t)(d0 + dr) * 2048 + s0 + sc) =
        *(const short8*)tmp;
  }
}

// ---------------------------------------------------------------------------
// Flash attention: window 1024 causal, softcap 50, scale 1/16.
// grid (S/64, H), block 256 (4 waves x 16 q-rows).
// ---------------------------------------------------------------------------
__global__ __launch_bounds__(256) void attn_kernel(
    const u16* __restrict__ qkv, const u16* __restrict__ vT,
    u16* __restrict__ aout)
{
  const int h = blockIdx.y, kvh = h >> 1;
  const int q0 = blockIdx.x * 64;
  const int tid = threadIdx.x;
  const int wave = tid >> 6, lane = tid & 63;
  const int lane15 = lane & 15, quad = lane >> 4;

  __shared__ __attribute__((aligned(16))) u16 KVs[256 * 72];
  __shared__ __attribute__((aligned(16))) u16 Ps[4][16 * 72];

  short8 aq[8];
  const u16* qrow = qkv + (size_t)(q0 + wave * 16 + lane15) * 8192 + h * 256;
#pragma unroll
  for (int kt = 0; kt < 8; kt++)
    aq[kt] = *(const short8*)(qrow + kt * 32 + quad * 8);

  floatx4 zero = {0.0f, 0.0f, 0.0f, 0.0f};
  floatx4 accO[16];
#pragma unroll
  for (int i = 0; i < 16; i++) accO[i] = zero;
  float mR[4], lR[4];
#pragma unroll
  for (int r = 0; r < 4; r++) { mR[r] = -1e30f; lR[r] = 0.0f; }

  const int iRow = q0 + wave * 16 + quad * 4;
  const int kb_lo = (q0 >= 1023) ? ((q0 - 1023) >> 6) : 0;
  const int kb_hi = q0 >> 6;

  for (int kb = kb_lo; kb <= kb_hi; kb++) {
    const int t0 = kb << 6;
#pragma unroll
    for (int i = 0; i < 8; i++) {
      int c = tid + i * 256;
      int r = c >> 5, dc = (c & 31) << 3;
      *(short8*)(&KVs[r * 264 + dc]) =
          *(const short8*)(qkv + (size_t)(t0 + r) * 8192 + 4096 + kvh * 256 + dc);
    }
    __syncthreads();

    floatx4 sAcc[4];
#pragma unroll
    for (int ni = 0; ni < 4; ni++) sAcc[ni] = zero;
#pragma unroll
    for (int kt = 0; kt < 8; kt++) {
#pragma unroll
      for (int ni = 0; ni < 4; ni++) {
        short8 bk = *(const short8*)(&KVs[(ni * 16 + lane15) * 264 + kt * 32 + quad * 8]);
        sAcc[ni] = __builtin_amdgcn_mfma_f32_16x16x32_bf16(aq[kt], bk, sAcc[ni], 0, 0, 0);
      }
    }

    float pv[4][4];
#pragma unroll
    for (int ni = 0; ni < 4; ni++)
#pragma unroll
      for (int r = 0; r < 4; r++) {
        float sv = sAcc[ni][r] * 0.0625f;
        sv = 50.0f * tanhf(sv * 0.02f);
        int i_ = iRow + r;
        int j_ = t0 + ni * 16 + lane15;
        bool ok = (j_ <= i_) && (i_ - j_ < 1024);
        pv[ni][r] = ok ? sv : -1e30f;
      }
    float alpha[4], mNew[4];
#pragma unroll
    for (int r = 0; r < 4; r++) {
      float mx = fmaxf(fmaxf(pv[0][r], pv[1][r]), fmaxf(pv[2][r], pv[3][r]));
      mx = fmaxf(mx, __shfl_xor(mx, 1));
      mx = fmaxf(mx, __shfl_xor(mx, 2));
      mx = fmaxf(mx, __shfl_xor(mx, 4));
      mx = fmaxf(mx, __shfl_xor(mx, 8));
      mNew[r] = fmaxf(mR[r], mx);
      alpha[r] = __expf(mR[r] - mNew[r]);
      mR[r] = mNew[r];
    }
#pragma unroll
    for (int ni = 0; ni < 4; ni++)
#pragma unroll
      for (int r = 0; r < 4; r++)
        pv[ni][r] = (pv[ni][r] > -1e29f) ? __expf(pv[ni][r] - mNew[r]) : 0.0f;
#pragma unroll
    for (int r = 0; r < 4; r++) {
      float sm = pv[0][r] + pv[1][r] + pv[2][r] + pv[3][r];
      sm += __shfl_xor(sm, 1);
      sm += __shfl_xor(sm, 2);
      sm += __shfl_xor(sm, 4);
      sm += __shfl_xor(sm, 8);
      lR[r] = lR[r] * alpha[r] + sm;
    }
#pragma unroll
    for (int ni = 0; ni < 16; ni++)
#pragma unroll
      for (int r = 0; r < 4; r++) accO[ni][r] *= alpha[r];

#pragma unroll
    for (int ni = 0; ni < 4; ni++)
#pragma unroll
      for (int r = 0; r < 4; r++)
        Ps[wave][(quad * 4 + r) * 72 + ni * 16 + lane15] = f2bf(pv[ni][r]);
    __syncthreads();  // K reads done; safe to overwrite KVs with V^T

#pragma unroll
    for (int i = 0; i < 8; i++) {
      int c = tid + i * 256;
      int dr = c >> 3, tc = (c & 7) << 3;
      *(short8*)(&KVs[dr * 72 + tc]) =
          *(const short8*)(vT + (size_t)kvh * 524288 + (size_t)dr * 2048 + t0 + tc);
    }
    __syncthreads();

#pragma unroll
    for (int ktile = 0; ktile < 2; ktile++) {
      short8 ap = *(const short8*)(&Ps[wave][lane15 * 72 + ktile * 32 + quad * 8]);
#pragma unroll
      for (int ni = 0; ni < 16; ni++) {
        short8 bv = *(const short8*)(&KVs[(ni * 16 + lane15) * 72 + ktile * 32 + quad * 8]);
        accO[ni] = __builtin_amdgcn_mfma_f32_16x16x32_bf16(ap, bv, accO[ni], 0, 0, 0);
      }
    }
    __syncthreads();
  }

#pragma unroll
  for (int r = 0; r < 4; r++) {
    float invl = 1.0f / lR[r];
    u16* orow = aout + (size_t)(q0 + wave * 16 + quad * 4 + r) * 4096 + h * 256;
#pragma unroll
    for (int ni = 0; ni < 16; ni++)
      orow[ni * 16 + lane15] = f2bf(accO[ni][r] * invl);
  }
}

// ---------------------------------------------------------------------------
extern "C" void kernel_launch(void* const* d_in, const int* in_sizes, int n_in,
                              void* d_out, int out_size, void* d_ws, size_t ws_size,
                              hipStream_t stream)
{
  const void* hidden = d_in[0];
  const void* w_qkv  = d_in[1];
  const void* w_o    = d_in[2];
  const void* q_w    = d_in[3];
  const void* k_w    = d_in[4];
  const void* cosb   = d_in[5];
  const void* sinb   = d_in[6];

  int* flag = (int*)d_ws;
  u16* qkv  = (u16*)((char*)d_ws + 256);       // 2048*8192 bf16 = 32 MB
  u16* vT   = qkv + (size_t)2048 * 8192;       // 8*256*2048 bf16 = 8 MB
  u16* aout = vT + (size_t)8 * 256 * 2048;     // 2048*4096 bf16 = 16 MB

  // 0) detect input dtype (fp32 vs bf16)
  probe_dtype_kernel<<<1, 256, 0, stream>>>(hidden, flag);
  // 1) qkv = hidden @ w_qkv   (2048 x 8192 x 3584)
  gemm_dyn_kernel<<<dim3(64, 16), 256, 0, stream>>>(hidden, w_qkv, qkv,
      2048, 8192, 3584, flag, 1, 1, 0);
  // 2) rms-norm + rope in place
  normrope_kernel<<<dim3(2048, 24), 256, 0, stream>>>(qkv, q_w, k_w, cosb, sinb, flag);
  // 3) v transpose
  vtrans_kernel<<<dim3(32, 4, 8), 256, 0, stream>>>(qkv, vT);
  // 4) flash attention
  attn_kernel<<<dim3(32, 16), 256, 0, stream>>>(qkv, vT, aout);
  // 5) out = aout @ w_o   (2048 x 3584 x 4096), output in harness dtype
  gemm_dyn_kernel<<<dim3(28, 16), 256, 0, stream>>>(aout, w_o, d_out,
      2048, 3584, 4096, flag, 0, 1, 1);
}

// Round 3
// 730.845 us; speedup vs baseline: 1.8313x; 1.8313x over previous
//
#include <hip/hip_runtime.h>
#include <hip/hip_bf16.h>
#include <math.h>

typedef __attribute__((ext_vector_type(8))) short short8;
typedef __attribute__((ext_vector_type(4))) float floatx4;
typedef unsigned short u16;

typedef __attribute__((address_space(1))) const void* gas_ptr;
typedef __attribute__((address_space(3))) void* las_ptr;

__device__ __forceinline__ float bf2f(u16 h) {
  union { unsigned u; float f; } v; v.u = ((unsigned)h) << 16; return v.f;
}
__device__ __forceinline__ u16 f2bf(float f) {
  union { float f; unsigned u; } v; v.f = f;
  unsigned r = v.u + 0x7FFFu + ((v.u >> 16) & 1u);
  return (u16)(r >> 16);
}
__device__ __forceinline__ float ldf_dyn(const void* p, size_t i, bool f32) {
  return f32 ? ((const float*)p)[i] : bf2f(((const u16*)p)[i]);
}
__device__ __forceinline__ short8 load8_dyn(const void* p, size_t idx, bool f32) {
  if (f32) {
    const float* f = (const float*)p;
    float4 a = *(const float4*)(f + idx);
    float4 b = *(const float4*)(f + idx + 4);
    short8 r;
    r[0] = (short)f2bf(a.x); r[1] = (short)f2bf(a.y);
    r[2] = (short)f2bf(a.z); r[3] = (short)f2bf(a.w);
    r[4] = (short)f2bf(b.x); r[5] = (short)f2bf(b.y);
    r[6] = (short)f2bf(b.z); r[7] = (short)f2bf(b.w);
    return r;
  }
  return *(const short8*)((const u16*)p + idx);
}
// async 16B global->LDS (lane l lands at lds + 16*l; lds must be wave-uniform)
__device__ __forceinline__ void gl_lds16(const u16* g, u16* l) {
  __builtin_amdgcn_global_load_lds((gas_ptr)g, (las_ptr)l, 16, 0, 0);
}

// ---------------------------------------------------------------------------
// Probe input dtype (fp32 vs bf16) from exponent statistics. flag=1 -> fp32.
// ---------------------------------------------------------------------------
__global__ void probe_dtype_kernel(const void* hidden, int* flag) {
  __shared__ int cnt;
  if (threadIdx.x == 0) cnt = 0;
  __syncthreads();
  const u16* h = (const u16*)hidden;
  int local = 0;
  for (int i = threadIdx.x; i < 8192; i += 256) {
    u16 u = h[i];
    int e = (u >> 7) & 0xFF;
    if ((e >= 64 && e <= 160) || (u & 0x7FFF) == 0) local++;
  }
  atomicAdd(&cnt, local);
  __syncthreads();
  if (threadIdx.x == 0) *flag = (cnt < 7700) ? 1 : 0;
}

// ---------------------------------------------------------------------------
// Elementwise convert harness dtype -> bf16.  n must be multiple of 8.
// ---------------------------------------------------------------------------
__global__ __launch_bounds__(256) void convert_dyn_kernel(
    const void* __restrict__ src, u16* __restrict__ dst, size_t n,
    const int* __restrict__ flagp)
{
  const bool f32 = (*flagp != 0);
  size_t i = ((size_t)blockIdx.x * 256 + threadIdx.x) * 8;
  if (i < n) *(short8*)(dst + i) = load8_dyn(src, i, f32);
}

// ---------------------------------------------------------------------------
// Transpose + convert: dst[c][r] = bf16(src[r][c]); src R x C (harness dtype).
// grid (C/64, R/64), block 256, 64x64 LDS tiles.
// ---------------------------------------------------------------------------
__global__ __launch_bounds__(256) void transpose_dyn_kernel(
    const void* __restrict__ src, u16* __restrict__ dst, int R, int C,
    const int* __restrict__ flagp)
{
  const bool f32 = (*flagp != 0);
  const int c0 = blockIdx.x * 64, r0 = blockIdx.y * 64;
  __shared__ __attribute__((aligned(16))) u16 T[64][72];
  const int tid = threadIdx.x;
#pragma unroll
  for (int i = 0; i < 2; i++) {
    int t = tid + i * 256;
    int r = t >> 3, cc = (t & 7) << 3;
    *(short8*)(&T[r][cc]) = load8_dyn(src, (size_t)(r0 + r) * C + c0 + cc, f32);
  }
  __syncthreads();
#pragma unroll
  for (int i = 0; i < 2; i++) {
    int t = tid + i * 256;
    int cr = t >> 3, rc = (t & 7) << 3;
    __attribute__((aligned(16))) u16 tmp[8];
#pragma unroll
    for (int j = 0; j < 8; j++) tmp[j] = T[rc + j][cr];
    *(short8*)(dst + (size_t)(c0 + cr) * R + r0 + rc) = *(const short8*)tmp;
  }
}

// ---------------------------------------------------------------------------
// GEMM (m97 structure): C[M,N] = A[M,K] * BT[N,K]^T, bf16 in, fp32 acc.
// 128x128 tile, BK=32, 256 threads, global_load_lds width-16 staging,
// unpadded [128][32] LDS tiles, ds_read_b128 fragments, 4x4 MFMA per wave.
// C written fp32/bf16 per (cdyn && *flagp).
// ---------------------------------------------------------------------------
__global__ __launch_bounds__(256) void gemm_bt_kernel(
    const u16* __restrict__ A, const u16* __restrict__ BT, void* __restrict__ C,
    int M, int N, int K, const int* __restrict__ flagp, int cdyn)
{
  __shared__ __attribute__((aligned(16))) u16 As[128 * 32];
  __shared__ __attribute__((aligned(16))) u16 Bs[128 * 32];
  const int tid = threadIdx.x;
  const int wave = tid >> 6, lane = tid & 63;
  const int lane15 = lane & 15, quad = lane >> 4;
  const int wr = (wave >> 1) * 64, wc = (wave & 1) * 64;
  const int m0 = blockIdx.y * 128, n0 = blockIdx.x * 128;

  // staging chunk map: chunk c in [0,512): LDS bytes c*16; row=c>>2, k=(c&3)*8
  const int ch0 = wave * 64 + lane;       // issue 0
  const int ch1 = ch0 + 256;              // issue 1
  const int sr0 = ch0 >> 2, sk0 = (ch0 & 3) << 3;
  const int sr1 = ch1 >> 2, sk1 = (ch1 & 3) << 3;
  u16* ldsA0 = &As[wave * 512];
  u16* ldsA1 = &As[2048 + wave * 512];
  u16* ldsB0 = &Bs[wave * 512];
  u16* ldsB1 = &Bs[2048 + wave * 512];
  const u16* Abase = A + (size_t)m0 * K;
  const u16* Bbase = BT + (size_t)n0 * K;

  floatx4 zero = {0.0f, 0.0f, 0.0f, 0.0f};
  floatx4 acc[4][4];
#pragma unroll
  for (int i = 0; i < 4; i++)
#pragma unroll
    for (int j = 0; j < 4; j++) acc[i][j] = zero;

  for (int k0 = 0; k0 < K; k0 += 32) {
    gl_lds16(Abase + (size_t)sr0 * K + k0 + sk0, ldsA0);
    gl_lds16(Abase + (size_t)sr1 * K + k0 + sk1, ldsA1);
    gl_lds16(Bbase + (size_t)sr0 * K + k0 + sk0, ldsB0);
    gl_lds16(Bbase + (size_t)sr1 * K + k0 + sk1, ldsB1);
    __syncthreads();
    short8 af[4], bfr[4];
#pragma unroll
    for (int mi = 0; mi < 4; mi++)
      af[mi] = *(const short8*)(&As[(wr + mi * 16 + lane15) * 32 + quad * 8]);
#pragma unroll
    for (int ni = 0; ni < 4; ni++)
      bfr[ni] = *(const short8*)(&Bs[(wc + ni * 16 + lane15) * 32 + quad * 8]);
#pragma unroll
    for (int mi = 0; mi < 4; mi++)
#pragma unroll
      for (int ni = 0; ni < 4; ni++)
        acc[mi][ni] = __builtin_amdgcn_mfma_f32_16x16x32_bf16(
            af[mi], bfr[ni], acc[mi][ni], 0, 0, 0);
    __syncthreads();
  }
  // C/D layout: col=lane&15, row=quad*4+r (m89-verified)
  const bool cf32 = cdyn && (*flagp != 0);
  if (cf32) {
    float* Cf = (float*)C;
#pragma unroll
    for (int mi = 0; mi < 4; mi++)
#pragma unroll
      for (int r = 0; r < 4; r++) {
        int m = m0 + wr + mi * 16 + quad * 4 + r;
        float* crow = Cf + (size_t)m * N + n0 + wc;
#pragma unroll
        for (int ni = 0; ni < 4; ni++) crow[ni * 16 + lane15] = acc[mi][ni][r];
      }
  } else {
    u16* Cb = (u16*)C;
#pragma unroll
    for (int mi = 0; mi < 4; mi++)
#pragma unroll
      for (int r = 0; r < 4; r++) {
        int m = m0 + wr + mi * 16 + quad * 4 + r;
        u16* crow = Cb + (size_t)m * N + n0 + wc;
#pragma unroll
        for (int ni = 0; ni < 4; ni++) crow[ni * 16 + lane15] = f2bf(acc[mi][ni][r]);
      }
  }
}

// ---------------------------------------------------------------------------
// RMS-norm + RoPE in place on q (16 heads) and k (8 heads). grid (S,24).
// ---------------------------------------------------------------------------
__global__ __launch_bounds__(256) void normrope_kernel(
    u16* __restrict__ qkv, const void* __restrict__ qw,
    const void* __restrict__ kw, const void* __restrict__ cosb,
    const void* __restrict__ sinb, const int* __restrict__ flagp)
{
  const bool f32 = (*flagp != 0);
  const int s = blockIdx.x;
  const int hh = blockIdx.y;
  const int d = threadIdx.x;
  const int col = (hh < 16) ? hh * 256 : 4096 + (hh - 16) * 256;
  const void* w = (hh < 16) ? qw : kw;
  u16* row = qkv + (size_t)s * 8192 + col;

  float x = bf2f(row[d]);
  int pd = (d < 128) ? d + 128 : d - 128;
  float xp = bf2f(row[pd]);

  float ss = x * x;
#pragma unroll
  for (int off = 32; off > 0; off >>= 1) ss += __shfl_xor(ss, off);
  __shared__ float red[4];
  if ((threadIdx.x & 63) == 0) red[threadIdx.x >> 6] = ss;
  __syncthreads();
  float tot = red[0] + red[1] + red[2] + red[3];
  float inv = rsqrtf(tot * (1.0f / 256.0f) + 1e-6f);

  float g = 1.0f + ldf_dyn(w, d, f32);
  float gp = 1.0f + ldf_dyn(w, pd, f32);
  float y = x * inv * g;
  float yp = xp * inv * gp;
  float rot = (d < 128) ? -yp : yp;
  float c = ldf_dyn(cosb, (size_t)s * 256 + d, f32);
  float sn = ldf_dyn(sinb, (size_t)s * 256 + d, f32);
  float outv = y * c + rot * sn;
  __syncthreads();
  row[d] = f2bf(outv);
}

// ---------------------------------------------------------------------------
// V transpose: vT[kv][d][s] = qkv[s][6144 + kv*256 + d]. grid (32,4,8).
// ---------------------------------------------------------------------------
__global__ __launch_bounds__(256) void vtrans_kernel(
    const u16* __restrict__ qkv, u16* __restrict__ vT)
{
  const int s0 = blockIdx.x * 64, d0 = blockIdx.y * 64, kv = blockIdx.z;
  __shared__ __attribute__((aligned(16))) u16 T[64][72];
  const int tid = threadIdx.x;
#pragma unroll
  for (int i = 0; i < 2; i++) {
    int c = tid + i * 256;
    int r = c >> 3, dc = (c & 7) << 3;
    *(short8*)(&T[r][dc]) =
        *(const short8*)(qkv + (size_t)(s0 + r) * 8192 + 6144 + kv * 256 + d0 + dc);
  }
  __syncthreads();
#pragma unroll
  for (int i = 0; i < 2; i++) {
    int c = tid + i * 256;
    int dr = c >> 3, sc = (c & 7) << 3;
    __attribute__((aligned(16))) u16 tmp[8];
#pragma unroll
    for (int j = 0; j < 8; j++) tmp[j] = T[sc + j][dr];
    *(short8*)(vT + (size_t)kv * 524288 + (size_t)(d0 + dr) * 2048 + s0 + sc) =
        *(const short8*)tmp;
  }
}

// ---------------------------------------------------------------------------
// Flash attention: window 1024 causal, softcap 50, scale 1/16.
// grid (S/64, H), block 256 (4 waves x 16 q-rows).
// ---------------------------------------------------------------------------
__global__ __launch_bounds__(256) void attn_kernel(
    const u16* __restrict__ qkv, const u16* __restrict__ vT,
    u16* __restrict__ aout)
{
  const int h = blockIdx.y, kvh = h >> 1;
  const int q0 = blockIdx.x * 64;
  const int tid = threadIdx.x;
  const int wave = tid >> 6, lane = tid & 63;
  const int lane15 = lane & 15, quad = lane >> 4;

  __shared__ __attribute__((aligned(16))) u16 KVs[256 * 72];
  __shared__ __attribute__((aligned(16))) u16 Ps[4][16 * 72];

  short8 aq[8];
  const u16* qrow = qkv + (size_t)(q0 + wave * 16 + lane15) * 8192 + h * 256;
#pragma unroll
  for (int kt = 0; kt < 8; kt++)
    aq[kt] = *(const short8*)(qrow + kt * 32 + quad * 8);

  floatx4 zero = {0.0f, 0.0f, 0.0f, 0.0f};
  floatx4 accO[16];
#pragma unroll
  for (int i = 0; i < 16; i++) accO[i] = zero;
  float mR[4], lR[4];
#pragma unroll
  for (int r = 0; r < 4; r++) { mR[r] = -1e30f; lR[r] = 0.0f; }

  const int iRow = q0 + wave * 16 + quad * 4;
  const int kb_lo = (q0 >= 1023) ? ((q0 - 1023) >> 6) : 0;
  const int kb_hi = q0 >> 6;

  for (int kb = kb_lo; kb <= kb_hi; kb++) {
    const int t0 = kb << 6;
#pragma unroll
    for (int i = 0; i < 8; i++) {
      int c = tid + i * 256;
      int r = c >> 5, dc = (c & 31) << 3;
      *(short8*)(&KVs[r * 264 + dc]) =
          *(const short8*)(qkv + (size_t)(t0 + r) * 8192 + 4096 + kvh * 256 + dc);
    }
    __syncthreads();

    floatx4 sAcc[4];
#pragma unroll
    for (int ni = 0; ni < 4; ni++) sAcc[ni] = zero;
#pragma unroll
    for (int kt = 0; kt < 8; kt++) {
#pragma unroll
      for (int ni = 0; ni < 4; ni++) {
        short8 bk = *(const short8*)(&KVs[(ni * 16 + lane15) * 264 + kt * 32 + quad * 8]);
        sAcc[ni] = __builtin_amdgcn_mfma_f32_16x16x32_bf16(aq[kt], bk, sAcc[ni], 0, 0, 0);
      }
    }

    float pv[4][4];
#pragma unroll
    for (int ni = 0; ni < 4; ni++)
#pragma unroll
      for (int r = 0; r < 4; r++) {
        float sv = sAcc[ni][r] * 0.0625f;
        sv = 50.0f * tanhf(sv * 0.02f);
        int i_ = iRow + r;
        int j_ = t0 + ni * 16 + lane15;
        bool ok = (j_ <= i_) && (i_ - j_ < 1024);
        pv[ni][r] = ok ? sv : -1e30f;
      }
    float alpha[4], mNew[4];
#pragma unroll
    for (int r = 0; r < 4; r++) {
      float mx = fmaxf(fmaxf(pv[0][r], pv[1][r]), fmaxf(pv[2][r], pv[3][r]));
      mx = fmaxf(mx, __shfl_xor(mx, 1));
      mx = fmaxf(mx, __shfl_xor(mx, 2));
      mx = fmaxf(mx, __shfl_xor(mx, 4));
      mx = fmaxf(mx, __shfl_xor(mx, 8));
      mNew[r] = fmaxf(mR[r], mx);
      alpha[r] = __expf(mR[r] - mNew[r]);
      mR[r] = mNew[r];
    }
#pragma unroll
    for (int ni = 0; ni < 4; ni++)
#pragma unroll
      for (int r = 0; r < 4; r++)
        pv[ni][r] = (pv[ni][r] > -1e29f) ? __expf(pv[ni][r] - mNew[r]) : 0.0f;
#pragma unroll
    for (int r = 0; r < 4; r++) {
      float sm = pv[0][r] + pv[1][r] + pv[2][r] + pv[3][r];
      sm += __shfl_xor(sm, 1);
      sm += __shfl_xor(sm, 2);
      sm += __shfl_xor(sm, 4);
      sm += __shfl_xor(sm, 8);
      lR[r] = lR[r] * alpha[r] + sm;
    }
#pragma unroll
    for (int ni = 0; ni < 16; ni++)
#pragma unroll
      for (int r = 0; r < 4; r++) accO[ni][r] *= alpha[r];

#pragma unroll
    for (int ni = 0; ni < 4; ni++)
#pragma unroll
      for (int r = 0; r < 4; r++)
        Ps[wave][(quad * 4 + r) * 72 + ni * 16 + lane15] = f2bf(pv[ni][r]);
    __syncthreads();

#pragma unroll
    for (int i = 0; i < 8; i++) {
      int c = tid + i * 256;
      int dr = c >> 3, tc = (c & 7) << 3;
      *(short8*)(&KVs[dr * 72 + tc]) =
          *(const short8*)(vT + (size_t)kvh * 524288 + (size_t)dr * 2048 + t0 + tc);
    }
    __syncthreads();

#pragma unroll
    for (int ktile = 0; ktile < 2; ktile++) {
      short8 ap = *(const short8*)(&Ps[wave][lane15 * 72 + ktile * 32 + quad * 8]);
#pragma unroll
      for (int ni = 0; ni < 16; ni++) {
        short8 bv = *(const short8*)(&KVs[(ni * 16 + lane15) * 72 + ktile * 32 + quad * 8]);
        accO[ni] = __builtin_amdgcn_mfma_f32_16x16x32_bf16(ap, bv, accO[ni], 0, 0, 0);
      }
    }
    __syncthreads();
  }

#pragma unroll
  for (int r = 0; r < 4; r++) {
    float invl = 1.0f / lR[r];
    u16* orow = aout + (size_t)(q0 + wave * 16 + quad * 4 + r) * 4096 + h * 256;
#pragma unroll
    for (int ni = 0; ni < 16; ni++)
      orow[ni * 16 + lane15] = f2bf(accO[ni][r] * invl);
  }
}

// ---------------------------------------------------------------------------
extern "C" void kernel_launch(void* const* d_in, const int* in_sizes, int n_in,
                              void* d_out, int out_size, void* d_ws, size_t ws_size,
                              hipStream_t stream)
{
  const void* hidden = d_in[0];
  const void* w_qkv  = d_in[1];
  const void* w_o    = d_in[2];
  const void* q_w    = d_in[3];
  const void* k_w    = d_in[4];
  const void* cosb   = d_in[5];
  const void* sinb   = d_in[6];

  char* ws = (char*)d_ws;
  int* flag = (int*)ws;                                   ws += 256;
  u16* qkv  = (u16*)ws;  ws += (size_t)2048 * 8192 * 2;   // 32 MB
  u16* vT   = (u16*)ws;  ws += (size_t)8 * 256 * 2048 * 2; // 8 MB
  u16* aout = (u16*)ws;  ws += (size_t)2048 * 4096 * 2;   // 16 MB
  u16* hb   = (u16*)ws;  ws += (size_t)2048 * 3584 * 2;   // 14.7 MB
  u16* wT   = (u16*)ws;  // 58.7 MB (shared: w_qkv^T then w_o^T)

  // 0) detect input dtype
  probe_dtype_kernel<<<1, 256, 0, stream>>>(hidden, flag);
  // 1) hidden -> bf16
  convert_dyn_kernel<<<3584, 256, 0, stream>>>(hidden, hb, (size_t)2048 * 3584, flag);
  // 2) w_qkv [3584][8192] -> wT [8192][3584] bf16
  transpose_dyn_kernel<<<dim3(128, 56), 256, 0, stream>>>(w_qkv, wT, 3584, 8192, flag);
  // 3) qkv = hb @ wT^T   (2048 x 8192 x 3584)
  gemm_bt_kernel<<<dim3(64, 16), 256, 0, stream>>>(hb, wT, qkv, 2048, 8192, 3584, flag, 0);
  // 4) rms-norm + rope in place
  normrope_kernel<<<dim3(2048, 24), 256, 0, stream>>>(qkv, q_w, k_w, cosb, sinb, flag);
  // 5) w_o [4096][3584] -> wT [3584][4096] bf16 (after gemm 3 is done with wT)
  transpose_dyn_kernel<<<dim3(56, 64), 256, 0, stream>>>(w_o, wT, 4096, 3584, flag);
  // 6) v transpose
  vtrans_kernel<<<dim3(32, 4, 8), 256, 0, stream>>>(qkv, vT);
  // 7) flash attention
  attn_kernel<<<dim3(32, 16), 256, 0, stream>>>(qkv, vT, aout);
  // 8) out = aout @ wT^T  (2048 x 3584 x 4096), harness output dtype
  gemm_bt_kernel<<<dim3(28, 16), 256, 0, stream>>>(aout, wT, d_out, 2048, 3584, 4096, flag, 1);
}

// Round 4
// 703.570 us; speedup vs baseline: 1.9023x; 1.0388x over previous
//
#include <hip/hip_runtime.h>
#include <hip/hip_bf16.h>
#include <math.h>

typedef __attribute__((ext_vector_type(8))) short short8;
typedef __attribute__((ext_vector_type(4))) float floatx4;
typedef unsigned short u16;

typedef __attribute__((address_space(1))) const void* gas_ptr;
typedef __attribute__((address_space(3))) void* las_ptr;

__device__ __forceinline__ float bf2f(u16 h) {
  union { unsigned u; float f; } v; v.u = ((unsigned)h) << 16; return v.f;
}
__device__ __forceinline__ u16 f2bf(float f) {
  union { float f; unsigned u; } v; v.f = f;
  unsigned r = v.u + 0x7FFFu + ((v.u >> 16) & 1u);
  return (u16)(r >> 16);
}
__device__ __forceinline__ float ldf_dyn(const void* p, size_t i, bool f32) {
  return f32 ? ((const float*)p)[i] : bf2f(((const u16*)p)[i]);
}
__device__ __forceinline__ short8 load8_dyn(const void* p, size_t idx, bool f32) {
  if (f32) {
    const float* f = (const float*)p;
    float4 a = *(const float4*)(f + idx);
    float4 b = *(const float4*)(f + idx + 4);
    short8 r;
    r[0] = (short)f2bf(a.x); r[1] = (short)f2bf(a.y);
    r[2] = (short)f2bf(a.z); r[3] = (short)f2bf(a.w);
    r[4] = (short)f2bf(b.x); r[5] = (short)f2bf(b.y);
    r[6] = (short)f2bf(b.z); r[7] = (short)f2bf(b.w);
    return r;
  }
  return *(const short8*)((const u16*)p + idx);
}
__device__ __forceinline__ void gl_lds16(const u16* g, u16* l) {
  __builtin_amdgcn_global_load_lds((gas_ptr)g, (las_ptr)l, 16, 0, 0);
}

// ---------------------------------------------------------------------------
__global__ void probe_dtype_kernel(const void* hidden, int* flag) {
  __shared__ int cnt;
  if (threadIdx.x == 0) cnt = 0;
  __syncthreads();
  const u16* h = (const u16*)hidden;
  int local = 0;
  for (int i = threadIdx.x; i < 8192; i += 256) {
    u16 u = h[i];
    int e = (u >> 7) & 0xFF;
    if ((e >= 64 && e <= 160) || (u & 0x7FFF) == 0) local++;
  }
  atomicAdd(&cnt, local);
  __syncthreads();
  if (threadIdx.x == 0) *flag = (cnt < 7700) ? 1 : 0;
}

// ---------------------------------------------------------------------------
__global__ __launch_bounds__(256) void convert_dyn_kernel(
    const void* __restrict__ src, u16* __restrict__ dst, size_t n,
    const int* __restrict__ flagp)
{
  const bool f32 = (*flagp != 0);
  size_t i = ((size_t)blockIdx.x * 256 + threadIdx.x) * 8;
  if (i < n) *(short8*)(dst + i) = load8_dyn(src, i, f32);
}

// ---------------------------------------------------------------------------
__global__ __launch_bounds__(256) void transpose_dyn_kernel(
    const void* __restrict__ src, u16* __restrict__ dst, int R, int C,
    const int* __restrict__ flagp)
{
  const bool f32 = (*flagp != 0);
  const int c0 = blockIdx.x * 64, r0 = blockIdx.y * 64;
  __shared__ __attribute__((aligned(16))) u16 T[64][72];
  const int tid = threadIdx.x;
#pragma unroll
  for (int i = 0; i < 2; i++) {
    int t = tid + i * 256;
    int r = t >> 3, cc = (t & 7) << 3;
    *(short8*)(&T[r][cc]) = load8_dyn(src, (size_t)(r0 + r) * C + c0 + cc, f32);
  }
  __syncthreads();
#pragma unroll
  for (int i = 0; i < 2; i++) {
    int t = tid + i * 256;
    int cr = t >> 3, rc = (t & 7) << 3;
    __attribute__((aligned(16))) u16 tmp[8];
#pragma unroll
    for (int j = 0; j < 8; j++) tmp[j] = T[rc + j][cr];
    *(short8*)(dst + (size_t)(c0 + cr) * R + r0 + rc) = *(const short8*)tmp;
  }
}

// ---------------------------------------------------------------------------
// GEMM (m97 structure + group swizzle): C = A[M,K] * BT[N,K]^T, bf16/fp32 acc.
// ---------------------------------------------------------------------------
__global__ __launch_bounds__(256) void gemm_bt_kernel(
    const u16* __restrict__ A, const u16* __restrict__ BT, void* __restrict__ C,
    int M, int N, int K, const int* __restrict__ flagp, int cdyn)
{
  __shared__ __attribute__((aligned(16))) u16 As[128 * 32];
  __shared__ __attribute__((aligned(16))) u16 Bs[128 * 32];
  const int tid = threadIdx.x;
  const int wave = tid >> 6, lane = tid & 63;
  const int lane15 = lane & 15, quad = lane >> 4;
  const int wr = (wave >> 1) * 64, wc = (wave & 1) * 64;

  // group swizzle: 8 n-blocks per group -> co-resident blocks share ~7 MB of B
  int idx = blockIdx.y * gridDim.x + blockIdx.x;
  int nig = 8 * gridDim.y;
  int grp = idx / nig;
  int rem = idx - grp * nig;
  int first_n = grp * 8;
  int gw = gridDim.x - first_n; gw = (gw > 8) ? 8 : gw;
  int mblk = rem / gw;
  int nblk = first_n + (rem - mblk * gw);
  const int m0 = mblk * 128, n0 = nblk * 128;

  const int ch0 = wave * 64 + lane;
  const int ch1 = ch0 + 256;
  const int sr0 = ch0 >> 2, sk0 = (ch0 & 3) << 3;
  const int sr1 = ch1 >> 2, sk1 = (ch1 & 3) << 3;
  u16* ldsA0 = &As[wave * 512];
  u16* ldsA1 = &As[2048 + wave * 512];
  u16* ldsB0 = &Bs[wave * 512];
  u16* ldsB1 = &Bs[2048 + wave * 512];
  const u16* pa0 = A + (size_t)(m0 + sr0) * K + sk0;
  const u16* pa1 = A + (size_t)(m0 + sr1) * K + sk1;
  const u16* pb0 = BT + (size_t)(n0 + sr0) * K + sk0;
  const u16* pb1 = BT + (size_t)(n0 + sr1) * K + sk1;

  floatx4 zero = {0.0f, 0.0f, 0.0f, 0.0f};
  floatx4 acc[4][4];
#pragma unroll
  for (int i = 0; i < 4; i++)
#pragma unroll
    for (int j = 0; j < 4; j++) acc[i][j] = zero;

  for (int k0 = 0; k0 < K; k0 += 32) {
    gl_lds16(pa0, ldsA0); gl_lds16(pa1, ldsA1);
    gl_lds16(pb0, ldsB0); gl_lds16(pb1, ldsB1);
    pa0 += 32; pa1 += 32; pb0 += 32; pb1 += 32;
    __syncthreads();
    short8 af[4], bfr[4];
#pragma unroll
    for (int mi = 0; mi < 4; mi++)
      af[mi] = *(const short8*)(&As[(wr + mi * 16 + lane15) * 32 + quad * 8]);
#pragma unroll
    for (int ni = 0; ni < 4; ni++)
      bfr[ni] = *(const short8*)(&Bs[(wc + ni * 16 + lane15) * 32 + quad * 8]);
#pragma unroll
    for (int mi = 0; mi < 4; mi++)
#pragma unroll
      for (int ni = 0; ni < 4; ni++)
        acc[mi][ni] = __builtin_amdgcn_mfma_f32_16x16x32_bf16(
            af[mi], bfr[ni], acc[mi][ni], 0, 0, 0);
    __syncthreads();
  }
  const bool cf32 = cdyn && (*flagp != 0);
  if (cf32) {
    float* Cf = (float*)C;
#pragma unroll
    for (int mi = 0; mi < 4; mi++)
#pragma unroll
      for (int r = 0; r < 4; r++) {
        int m = m0 + wr + mi * 16 + quad * 4 + r;
        float* crow = Cf + (size_t)m * N + n0 + wc;
#pragma unroll
        for (int ni = 0; ni < 4; ni++) crow[ni * 16 + lane15] = acc[mi][ni][r];
      }
  } else {
    u16* Cb = (u16*)C;
#pragma unroll
    for (int mi = 0; mi < 4; mi++)
#pragma unroll
      for (int r = 0; r < 4; r++) {
        int m = m0 + wr + mi * 16 + quad * 4 + r;
        u16* crow = Cb + (size_t)m * N + n0 + wc;
#pragma unroll
        for (int ni = 0; ni < 4; ni++) crow[ni * 16 + lane15] = f2bf(acc[mi][ni][r]);
      }
  }
}

// ---------------------------------------------------------------------------
__global__ __launch_bounds__(256) void normrope_kernel(
    u16* __restrict__ qkv, const void* __restrict__ qw,
    const void* __restrict__ kw, const void* __restrict__ cosb,
    const void* __restrict__ sinb, const int* __restrict__ flagp)
{
  const bool f32 = (*flagp != 0);
  const int s = blockIdx.x;
  const int hh = blockIdx.y;
  const int d = threadIdx.x;
  const int col = (hh < 16) ? hh * 256 : 4096 + (hh - 16) * 256;
  const void* w = (hh < 16) ? qw : kw;
  u16* row = qkv + (size_t)s * 8192 + col;

  float x = bf2f(row[d]);
  int pd = (d < 128) ? d + 128 : d - 128;
  float xp = bf2f(row[pd]);

  float ss = x * x;
#pragma unroll
  for (int off = 32; off > 0; off >>= 1) ss += __shfl_xor(ss, off);
  __shared__ float red[4];
  if ((threadIdx.x & 63) == 0) red[threadIdx.x >> 6] = ss;
  __syncthreads();
  float tot = red[0] + red[1] + red[2] + red[3];
  float inv = rsqrtf(tot * (1.0f / 256.0f) + 1e-6f);

  float g = 1.0f + ldf_dyn(w, d, f32);
  float gp = 1.0f + ldf_dyn(w, pd, f32);
  float y = x * inv * g;
  float yp = xp * inv * gp;
  float rot = (d < 128) ? -yp : yp;
  float c = ldf_dyn(cosb, (size_t)s * 256 + d, f32);
  float sn = ldf_dyn(sinb, (size_t)s * 256 + d, f32);
  float outv = y * c + rot * sn;
  __syncthreads();
  row[d] = f2bf(outv);
}

// ---------------------------------------------------------------------------
__global__ __launch_bounds__(256) void vtrans_kernel(
    const u16* __restrict__ qkv, u16* __restrict__ vT)
{
  const int s0 = blockIdx.x * 64, d0 = blockIdx.y * 64, kv = blockIdx.z;
  __shared__ __attribute__((aligned(16))) u16 T[64][72];
  const int tid = threadIdx.x;
#pragma unroll
  for (int i = 0; i < 2; i++) {
    int c = tid + i * 256;
    int r = c >> 3, dc = (c & 7) << 3;
    *(short8*)(&T[r][dc]) =
        *(const short8*)(qkv + (size_t)(s0 + r) * 8192 + 6144 + kv * 256 + d0 + dc);
  }
  __syncthreads();
#pragma unroll
  for (int i = 0; i < 2; i++) {
    int c = tid + i * 256;
    int dr = c >> 3, sc = (c & 7) << 3;
    __attribute__((aligned(16))) u16 tmp[8];
#pragma unroll
    for (int j = 0; j < 8; j++) tmp[j] = T[sc + j][dr];
    *(short8*)(vT + (size_t)kv * 524288 + (size_t)(d0 + dr) * 2048 + s0 + sc) =
        *(const short8*)tmp;
  }
}

// ---------------------------------------------------------------------------
// Flash attention: window 1024 causal, softcap 50, scale 1/16.
// Mask value -3000: scores are softcapped to |50|, so exp(-3000-m)==0 exactly,
// and rows whose prefix is fully masked get wiped by alpha=exp(-2950)=0 at
// their first live tile (diagonal guarantees one exists).
// ---------------------------------------------------------------------------
__global__ __launch_bounds__(256) void attn_kernel(
    const u16* __restrict__ qkv, const u16* __restrict__ vT,
    u16* __restrict__ aout)
{
  const int h = blockIdx.y, kvh = h >> 1;
  const int q0 = blockIdx.x * 64;
  const int tid = threadIdx.x;
  const int wave = tid >> 6, lane = tid & 63;
  const int lane15 = lane & 15, quad = lane >> 4;

  __shared__ __attribute__((aligned(16))) u16 KVs[256 * 72];
  __shared__ __attribute__((aligned(16))) u16 Ps[4][16 * 72];

  short8 aq[8];
  const u16* qrow = qkv + (size_t)(q0 + wave * 16 + lane15) * 8192 + h * 256;
#pragma unroll
  for (int kt = 0; kt < 8; kt++)
    aq[kt] = *(const short8*)(qrow + kt * 32 + quad * 8);

  floatx4 zero = {0.0f, 0.0f, 0.0f, 0.0f};
  floatx4 accO[16];
#pragma unroll
  for (int i = 0; i < 16; i++) accO[i] = zero;
  float mR[4], lR[4];
#pragma unroll
  for (int r = 0; r < 4; r++) { mR[r] = -3000.0f; lR[r] = 0.0f; }

  const int iRow = q0 + wave * 16 + quad * 4;
  const int kb_lo = (q0 >= 1023) ? ((q0 - 1023) >> 6) : 0;
  const int kb_hi = q0 >> 6;

  for (int kb = kb_lo; kb <= kb_hi; kb++) {
    const int t0 = kb << 6;
#pragma unroll
    for (int i = 0; i < 8; i++) {
      int c = tid + i * 256;
      int r = c >> 5, dc = (c & 31) << 3;
      *(short8*)(&KVs[r * 264 + dc]) =
          *(const short8*)(qkv + (size_t)(t0 + r) * 8192 + 4096 + kvh * 256 + dc);
    }
    __syncthreads();

    floatx4 sAcc[4];
#pragma unroll
    for (int ni = 0; ni < 4; ni++) sAcc[ni] = zero;
#pragma unroll
    for (int kt = 0; kt < 8; kt++) {
#pragma unroll
      for (int ni = 0; ni < 4; ni++) {
        short8 bk = *(const short8*)(&KVs[(ni * 16 + lane15) * 264 + kt * 32 + quad * 8]);
        sAcc[ni] = __builtin_amdgcn_mfma_f32_16x16x32_bf16(aq[kt], bk, sAcc[ni], 0, 0, 0);
      }
    }

    float pv[4][4];
#pragma unroll
    for (int ni = 0; ni < 4; ni++)
#pragma unroll
      for (int r = 0; r < 4; r++) {
        // 50*tanh(s/16/50) via exp+rcp (fast, |err| ~1e-7 rel)
        float x = sAcc[ni][r] * 0.00125f;
        float ax = __builtin_fabsf(x);
        float e2 = __expf(ax + ax);
        float t = 1.0f - 2.0f * __builtin_amdgcn_rcpf(e2 + 1.0f);
        float sv = copysignf(t, x) * 50.0f;
        int i_ = iRow + r;
        int j_ = t0 + ni * 16 + lane15;
        bool ok = (j_ <= i_) && (i_ - j_ < 1024);
        pv[ni][r] = ok ? sv : -3000.0f;
      }
    float alpha[4], mNew[4];
#pragma unroll
    for (int r = 0; r < 4; r++) {
      float mx = fmaxf(fmaxf(pv[0][r], pv[1][r]), fmaxf(pv[2][r], pv[3][r]));
      mx = fmaxf(mx, __shfl_xor(mx, 1));
      mx = fmaxf(mx, __shfl_xor(mx, 2));
      mx = fmaxf(mx, __shfl_xor(mx, 4));
      mx = fmaxf(mx, __shfl_xor(mx, 8));
      mNew[r] = fmaxf(mR[r], mx);
      alpha[r] = __expf(mR[r] - mNew[r]);
      mR[r] = mNew[r];
    }
#pragma unroll
    for (int ni = 0; ni < 4; ni++)
#pragma unroll
      for (int r = 0; r < 4; r++)
        pv[ni][r] = __expf(pv[ni][r] - mNew[r]);
#pragma unroll
    for (int r = 0; r < 4; r++) {
      float sm = pv[0][r] + pv[1][r] + pv[2][r] + pv[3][r];
      sm += __shfl_xor(sm, 1);
      sm += __shfl_xor(sm, 2);
      sm += __shfl_xor(sm, 4);
      sm += __shfl_xor(sm, 8);
      lR[r] = lR[r] * alpha[r] + sm;
    }
#pragma unroll
    for (int ni = 0; ni < 16; ni++)
#pragma unroll
      for (int r = 0; r < 4; r++) accO[ni][r] *= alpha[r];

#pragma unroll
    for (int ni = 0; ni < 4; ni++)
#pragma unroll
      for (int r = 0; r < 4; r++)
        Ps[wave][(quad * 4 + r) * 72 + ni * 16 + lane15] = f2bf(pv[ni][r]);
    __syncthreads();

#pragma unroll
    for (int i = 0; i < 8; i++) {
      int c = tid + i * 256;
      int dr = c >> 3, tc = (c & 7) << 3;
      *(short8*)(&KVs[dr * 72 + tc]) =
          *(const short8*)(vT + (size_t)kvh * 524288 + (size_t)dr * 2048 + t0 + tc);
    }
    __syncthreads();

#pragma unroll
    for (int ktile = 0; ktile < 2; ktile++) {
      short8 ap = *(const short8*)(&Ps[wave][lane15 * 72 + ktile * 32 + quad * 8]);
#pragma unroll
      for (int ni = 0; ni < 16; ni++) {
        short8 bv = *(const short8*)(&KVs[(ni * 16 + lane15) * 72 + ktile * 32 + quad * 8]);
        accO[ni] = __builtin_amdgcn_mfma_f32_16x16x32_bf16(ap, bv, accO[ni], 0, 0, 0);
      }
    }
    __syncthreads();
  }

#pragma unroll
  for (int r = 0; r < 4; r++) {
    float invl = 1.0f / lR[r];
    u16* orow = aout + (size_t)(q0 + wave * 16 + quad * 4 + r) * 4096 + h * 256;
#pragma unroll
    for (int ni = 0; ni < 16; ni++)
      orow[ni * 16 + lane15] = f2bf(accO[ni][r] * invl);
  }
}

// ---------------------------------------------------------------------------
extern "C" void kernel_launch(void* const* d_in, const int* in_sizes, int n_in,
                              void* d_out, int out_size, void* d_ws, size_t ws_size,
                              hipStream_t stream)
{
  const void* hidden = d_in[0];
  const void* w_qkv  = d_in[1];
  const void* w_o    = d_in[2];
  const void* q_w    = d_in[3];
  const void* k_w    = d_in[4];
  const void* cosb   = d_in[5];
  const void* sinb   = d_in[6];

  char* ws = (char*)d_ws;
  int* flag = (int*)ws;                                   ws += 256;
  u16* qkv  = (u16*)ws;  ws += (size_t)2048 * 8192 * 2;
  u16* vT   = (u16*)ws;  ws += (size_t)8 * 256 * 2048 * 2;
  u16* aout = (u16*)ws;  ws += (size_t)2048 * 4096 * 2;
  u16* hb   = (u16*)ws;  ws += (size_t)2048 * 3584 * 2;
  u16* wT   = (u16*)ws;

  probe_dtype_kernel<<<1, 256, 0, stream>>>(hidden, flag);
  convert_dyn_kernel<<<3584, 256, 0, stream>>>(hidden, hb, (size_t)2048 * 3584, flag);
  transpose_dyn_kernel<<<dim3(128, 56), 256, 0, stream>>>(w_qkv, wT, 3584, 8192, flag);
  gemm_bt_kernel<<<dim3(64, 16), 256, 0, stream>>>(hb, wT, qkv, 2048, 8192, 3584, flag, 0);
  normrope_kernel<<<dim3(2048, 24), 256, 0, stream>>>(qkv, q_w, k_w, cosb, sinb, flag);
  transpose_dyn_kernel<<<dim3(56, 64), 256, 0, stream>>>(w_o, wT, 4096, 3584, flag);
  vtrans_kernel<<<dim3(32, 4, 8), 256, 0, stream>>>(qkv, vT);
  attn_kernel<<<dim3(32, 16), 256, 0, stream>>>(qkv, vT, aout);
  gemm_bt_kernel<<<dim3(28, 16), 256, 0, stream>>>(aout, wT, d_out, 2048, 3584, 4096, flag, 1);
}

// Round 5
// 666.484 us; speedup vs baseline: 2.0082x; 1.0556x over previous
//
#include <hip/hip_runtime.h>
#include <hip/hip_bf16.h>
#include <math.h>

typedef __attribute__((ext_vector_type(8))) short short8;
typedef __attribute__((ext_vector_type(4))) float floatx4;
typedef unsigned short u16;

typedef __attribute__((address_space(1))) const void* gas_ptr;
typedef __attribute__((address_space(3))) void* las_ptr;

__device__ __forceinline__ float bf2f(u16 h) {
  union { unsigned u; float f; } v; v.u = ((unsigned)h) << 16; return v.f;
}
__device__ __forceinline__ u16 f2bf(float f) {
  union { float f; unsigned u; } v; v.f = f;
  unsigned r = v.u + 0x7FFFu + ((v.u >> 16) & 1u);
  return (u16)(r >> 16);
}
__device__ __forceinline__ float ldf_dyn(const void* p, size_t i, bool f32) {
  return f32 ? ((const float*)p)[i] : bf2f(((const u16*)p)[i]);
}
__device__ __forceinline__ short8 load8_dyn(const void* p, size_t idx, bool f32) {
  if (f32) {
    const float* f = (const float*)p;
    float4 a = *(const float4*)(f + idx);
    float4 b = *(const float4*)(f + idx + 4);
    short8 r;
    r[0] = (short)f2bf(a.x); r[1] = (short)f2bf(a.y);
    r[2] = (short)f2bf(a.z); r[3] = (short)f2bf(a.w);
    r[4] = (short)f2bf(b.x); r[5] = (short)f2bf(b.y);
    r[6] = (short)f2bf(b.z); r[7] = (short)f2bf(b.w);
    return r;
  }
  return *(const short8*)((const u16*)p + idx);
}
__device__ __forceinline__ void gl_lds16(const u16* g, u16* l) {
  __builtin_amdgcn_global_load_lds((gas_ptr)g, (las_ptr)l, 16, 0, 0);
}

// ---------------------------------------------------------------------------
__global__ void probe_dtype_kernel(const void* hidden, int* flag) {
  __shared__ int cnt;
  if (threadIdx.x == 0) cnt = 0;
  __syncthreads();
  const u16* h = (const u16*)hidden;
  int local = 0;
  for (int i = threadIdx.x; i < 8192; i += 256) {
    u16 u = h[i];
    int e = (u >> 7) & 0xFF;
    if ((e >= 64 && e <= 160) || (u & 0x7FFF) == 0) local++;
  }
  atomicAdd(&cnt, local);
  __syncthreads();
  if (threadIdx.x == 0) *flag = (cnt < 7700) ? 1 : 0;
}

// ---------------------------------------------------------------------------
__global__ __launch_bounds__(256) void convert_dyn_kernel(
    const void* __restrict__ src, u16* __restrict__ dst, size_t n,
    const int* __restrict__ flagp)
{
  const bool f32 = (*flagp != 0);
  size_t i = ((size_t)blockIdx.x * 256 + threadIdx.x) * 8;
  if (i < n) *(short8*)(dst + i) = load8_dyn(src, i, f32);
}

// ---------------------------------------------------------------------------
__global__ __launch_bounds__(256) void transpose_dyn_kernel(
    const void* __restrict__ src, u16* __restrict__ dst, int R, int C,
    const int* __restrict__ flagp)
{
  const bool f32 = (*flagp != 0);
  const int c0 = blockIdx.x * 64, r0 = blockIdx.y * 64;
  __shared__ __attribute__((aligned(16))) u16 T[64][72];
  const int tid = threadIdx.x;
#pragma unroll
  for (int i = 0; i < 2; i++) {
    int t = tid + i * 256;
    int r = t >> 3, cc = (t & 7) << 3;
    *(short8*)(&T[r][cc]) = load8_dyn(src, (size_t)(r0 + r) * C + c0 + cc, f32);
  }
  __syncthreads();
#pragma unroll
  for (int i = 0; i < 2; i++) {
    int t = tid + i * 256;
    int cr = t >> 3, rc = (t & 7) << 3;
    __attribute__((aligned(16))) u16 tmp[8];
#pragma unroll
    for (int j = 0; j < 8; j++) tmp[j] = T[rc + j][cr];
    *(short8*)(dst + (size_t)(c0 + cr) * R + r0 + rc) = *(const short8*)tmp;
  }
}

// ---------------------------------------------------------------------------
// GEMM (m97 structure, natural block order): C = A[M,K] * BT[N,K]^T.
// Natural bx-fastest order keeps co-resident blocks k-lockstep -> B slab
// stays L2/L3 resident (swizzle in r4 raised FETCH 125->176 MB; reverted).
// ---------------------------------------------------------------------------
__global__ __launch_bounds__(256) void gemm_bt_kernel(
    const u16* __restrict__ A, const u16* __restrict__ BT, void* __restrict__ C,
    int M, int N, int K, const int* __restrict__ flagp, int cdyn)
{
  __shared__ __attribute__((aligned(16))) u16 As[128 * 32];
  __shared__ __attribute__((aligned(16))) u16 Bs[128 * 32];
  const int tid = threadIdx.x;
  const int wave = tid >> 6, lane = tid & 63;
  const int lane15 = lane & 15, quad = lane >> 4;
  const int wr = (wave >> 1) * 64, wc = (wave & 1) * 64;
  const int m0 = blockIdx.y * 128, n0 = blockIdx.x * 128;

  const int ch0 = wave * 64 + lane;
  const int ch1 = ch0 + 256;
  const int sr0 = ch0 >> 2, sk0 = (ch0 & 3) << 3;
  const int sr1 = ch1 >> 2, sk1 = (ch1 & 3) << 3;
  u16* ldsA0 = &As[wave * 512];
  u16* ldsA1 = &As[2048 + wave * 512];
  u16* ldsB0 = &Bs[wave * 512];
  u16* ldsB1 = &Bs[2048 + wave * 512];
  const u16* pa0 = A + (size_t)(m0 + sr0) * K + sk0;
  const u16* pa1 = A + (size_t)(m0 + sr1) * K + sk1;
  const u16* pb0 = BT + (size_t)(n0 + sr0) * K + sk0;
  const u16* pb1 = BT + (size_t)(n0 + sr1) * K + sk1;

  floatx4 zero = {0.0f, 0.0f, 0.0f, 0.0f};
  floatx4 acc[4][4];
#pragma unroll
  for (int i = 0; i < 4; i++)
#pragma unroll
    for (int j = 0; j < 4; j++) acc[i][j] = zero;

  for (int k0 = 0; k0 < K; k0 += 32) {
    gl_lds16(pa0, ldsA0); gl_lds16(pa1, ldsA1);
    gl_lds16(pb0, ldsB0); gl_lds16(pb1, ldsB1);
    pa0 += 32; pa1 += 32; pb0 += 32; pb1 += 32;
    __syncthreads();
    short8 af[4], bfr[4];
#pragma unroll
    for (int mi = 0; mi < 4; mi++)
      af[mi] = *(const short8*)(&As[(wr + mi * 16 + lane15) * 32 + quad * 8]);
#pragma unroll
    for (int ni = 0; ni < 4; ni++)
      bfr[ni] = *(const short8*)(&Bs[(wc + ni * 16 + lane15) * 32 + quad * 8]);
#pragma unroll
    for (int mi = 0; mi < 4; mi++)
#pragma unroll
      for (int ni = 0; ni < 4; ni++)
        acc[mi][ni] = __builtin_amdgcn_mfma_f32_16x16x32_bf16(
            af[mi], bfr[ni], acc[mi][ni], 0, 0, 0);
    __syncthreads();
  }
  const bool cf32 = cdyn && (*flagp != 0);
  if (cf32) {
    float* Cf = (float*)C;
#pragma unroll
    for (int mi = 0; mi < 4; mi++)
#pragma unroll
      for (int r = 0; r < 4; r++) {
        int m = m0 + wr + mi * 16 + quad * 4 + r;
        float* crow = Cf + (size_t)m * N + n0 + wc;
#pragma unroll
        for (int ni = 0; ni < 4; ni++) crow[ni * 16 + lane15] = acc[mi][ni][r];
      }
  } else {
    u16* Cb = (u16*)C;
#pragma unroll
    for (int mi = 0; mi < 4; mi++)
#pragma unroll
      for (int r = 0; r < 4; r++) {
        int m = m0 + wr + mi * 16 + quad * 4 + r;
        u16* crow = Cb + (size_t)m * N + n0 + wc;
#pragma unroll
        for (int ni = 0; ni < 4; ni++) crow[ni * 16 + lane15] = f2bf(acc[mi][ni][r]);
      }
  }
}

// ---------------------------------------------------------------------------
// RMS-norm + RoPE, one wave per (s, head): lane holds d in {l, l+64, l+128,
// l+192}; rope partners are local; reduction is wave-shuffle only (no LDS).
// grid (S, 6), block 256 (4 waves = 4 heads).
// ---------------------------------------------------------------------------
__global__ __launch_bounds__(256) void normrope_kernel(
    u16* __restrict__ qkv, const void* __restrict__ qw,
    const void* __restrict__ kw, const void* __restrict__ cosb,
    const void* __restrict__ sinb, const int* __restrict__ flagp)
{
  const bool f32 = (*flagp != 0);
  const int s = blockIdx.x;
  const int wave = threadIdx.x >> 6, lane = threadIdx.x & 63;
  const int hh = blockIdx.y * 4 + wave;
  const int col = (hh < 16) ? hh * 256 : 4096 + (hh - 16) * 256;
  const void* w = (hh < 16) ? qw : kw;
  u16* row = qkv + (size_t)s * 8192 + col;

  float x[4];
#pragma unroll
  for (int j = 0; j < 4; j++) x[j] = bf2f(row[lane + j * 64]);

  float ss = x[0] * x[0] + x[1] * x[1] + x[2] * x[2] + x[3] * x[3];
#pragma unroll
  for (int off = 32; off > 0; off >>= 1) ss += __shfl_xor(ss, off);
  float inv = rsqrtf(ss * (1.0f / 256.0f) + 1e-6f);

  float y[4];
#pragma unroll
  for (int j = 0; j < 4; j++)
    y[j] = x[j] * inv * (1.0f + ldf_dyn(w, lane + j * 64, f32));
  // rot(d)=-y(d+128) for d<128; +y(d-128) else. Partners are local regs.
  float rot[4] = {-y[2], -y[3], y[0], y[1]};
#pragma unroll
  for (int j = 0; j < 4; j++) {
    int d = lane + j * 64;
    float c = ldf_dyn(cosb, (size_t)s * 256 + d, f32);
    float sn = ldf_dyn(sinb, (size_t)s * 256 + d, f32);
    row[d] = f2bf(y[j] * c + rot[j] * sn);
  }
}

// ---------------------------------------------------------------------------
__global__ __launch_bounds__(256) void vtrans_kernel(
    const u16* __restrict__ qkv, u16* __restrict__ vT)
{
  const int s0 = blockIdx.x * 64, d0 = blockIdx.y * 64, kv = blockIdx.z;
  __shared__ __attribute__((aligned(16))) u16 T[64][72];
  const int tid = threadIdx.x;
#pragma unroll
  for (int i = 0; i < 2; i++) {
    int c = tid + i * 256;
    int r = c >> 3, dc = (c & 7) << 3;
    *(short8*)(&T[r][dc]) =
        *(const short8*)(qkv + (size_t)(s0 + r) * 8192 + 6144 + kv * 256 + d0 + dc);
  }
  __syncthreads();
#pragma unroll
  for (int i = 0; i < 2; i++) {
    int c = tid + i * 256;
    int dr = c >> 3, sc = (c & 7) << 3;
    __attribute__((aligned(16))) u16 tmp[8];
#pragma unroll
    for (int j = 0; j < 8; j++) tmp[j] = T[sc + j][dr];
    *(short8*)(vT + (size_t)kv * 524288 + (size_t)(d0 + dr) * 2048 + s0 + sc) =
        *(const short8*)tmp;
  }
}

// ---------------------------------------------------------------------------
// Flash attention, FIXED-BASE softmax: scores are softcapped to [-50,50], so
// p=exp(s) can't overflow/underflow fp32 -> no running max, no alpha rescale,
// no per-tile cross-lane reductions. l reduced across lanes once at the end.
// Wave-uniform ni/kt bounds skip fully-masked 16-col QK / 32-col PV groups.
// ---------------------------------------------------------------------------
__global__ __launch_bounds__(256) void attn_kernel(
    const u16* __restrict__ qkv, const u16* __restrict__ vT,
    u16* __restrict__ aout)
{
  const int h = blockIdx.y, kvh = h >> 1;
  const int q0 = blockIdx.x * 64;
  const int tid = threadIdx.x;
  const int wave = tid >> 6, lane = tid & 63;
  const int lane15 = lane & 15, quad = lane >> 4;

  __shared__ __attribute__((aligned(16))) u16 KVs[256 * 72];
  __shared__ __attribute__((aligned(16))) u16 Ps[4][16 * 72];

  short8 aq[8];
  const u16* qrow = qkv + (size_t)(q0 + wave * 16 + lane15) * 8192 + h * 256;
#pragma unroll
  for (int kt = 0; kt < 8; kt++)
    aq[kt] = *(const short8*)(qrow + kt * 32 + quad * 8);

  floatx4 zero = {0.0f, 0.0f, 0.0f, 0.0f};
  floatx4 accO[16];
#pragma unroll
  for (int i = 0; i < 16; i++) accO[i] = zero;
  float lR[4] = {0.0f, 0.0f, 0.0f, 0.0f};

  const int iRow = q0 + wave * 16 + quad * 4;
  const int kb_lo = (q0 >= 1023) ? ((q0 - 1023) >> 6) : 0;
  const int kb_hi = q0 >> 6;

  for (int kb = kb_lo; kb <= kb_hi; kb++) {
    const int t0 = kb << 6;
#pragma unroll
    for (int i = 0; i < 8; i++) {
      int c = tid + i * 256;
      int r = c >> 5, dc = (c & 31) << 3;
      *(short8*)(&KVs[r * 264 + dc]) =
          *(const short8*)(qkv + (size_t)(t0 + r) * 8192 + 4096 + kvh * 256 + dc);
    }
    __syncthreads();

    // wave-uniform skip bounds (group fully above diagonal / below window)
    const int relHi = q0 + 16 * wave + 15 - t0;          // >= 0 always
    const int relLo = q0 + 16 * wave - 1023 - t0;        // may be negative
    const int niHiR = relHi >> 4;
    const int niHi = (niHiR > 3) ? 3 : niHiR;
    int niLo = relLo >> 4; if (niLo < 0) niLo = 0;
    const int ktHiR = relHi >> 5;
    const int ktHi = (ktHiR > 1) ? 1 : ktHiR;
    int ktLo = relLo >> 5; if (ktLo < 0) ktLo = 0;

    float pv[4][4];
#pragma unroll
    for (int ni = 0; ni < 4; ni++) {
      if (ni < niLo || ni > niHi) {
        pv[ni][0] = pv[ni][1] = pv[ni][2] = pv[ni][3] = 0.0f;
        continue;
      }
      floatx4 sAcc = zero;
#pragma unroll
      for (int kt = 0; kt < 8; kt++) {
        short8 bk = *(const short8*)(&KVs[(ni * 16 + lane15) * 264 + kt * 32 + quad * 8]);
        sAcc = __builtin_amdgcn_mfma_f32_16x16x32_bf16(aq[kt], bk, sAcc, 0, 0, 0);
      }
#pragma unroll
      for (int r = 0; r < 4; r++) {
        // s = 50*tanh(raw/16/50) via exp+rcp; p = exp(s) (fixed base, exact)
        float x = sAcc[r] * 0.00125f;
        float ax = __builtin_fabsf(x);
        float e2 = __expf(ax + ax);
        float t = 1.0f - 2.0f * __builtin_amdgcn_rcpf(e2 + 1.0f);
        float sv = copysignf(t, x) * 50.0f;
        int i_ = iRow + r;
        int j_ = t0 + ni * 16 + lane15;
        bool ok = (j_ <= i_) && (i_ - j_ < 1024);
        pv[ni][r] = ok ? __expf(sv) : 0.0f;
      }
    }
#pragma unroll
    for (int r = 0; r < 4; r++)
      lR[r] += pv[0][r] + pv[1][r] + pv[2][r] + pv[3][r];

#pragma unroll
    for (int ni = 0; ni < 4; ni++)
#pragma unroll
      for (int r = 0; r < 4; r++)
        Ps[wave][(quad * 4 + r) * 72 + ni * 16 + lane15] = f2bf(pv[ni][r]);
    __syncthreads();  // K reads done; reuse KVs for V^T

#pragma unroll
    for (int i = 0; i < 8; i++) {
      int c = tid + i * 256;
      int dr = c >> 3, tc = (c & 7) << 3;
      *(short8*)(&KVs[dr * 72 + tc]) =
          *(const short8*)(vT + (size_t)kvh * 524288 + (size_t)dr * 2048 + t0 + tc);
    }
    __syncthreads();

#pragma unroll
    for (int ktile = 0; ktile < 2; ktile++) {
      if (ktile < ktLo || ktile > ktHi) continue;
      short8 ap = *(const short8*)(&Ps[wave][lane15 * 72 + ktile * 32 + quad * 8]);
#pragma unroll
      for (int ni = 0; ni < 16; ni++) {
        short8 bv = *(const short8*)(&KVs[(ni * 16 + lane15) * 72 + ktile * 32 + quad * 8]);
        accO[ni] = __builtin_amdgcn_mfma_f32_16x16x32_bf16(ap, bv, accO[ni], 0, 0, 0);
      }
    }
    __syncthreads();
  }

#pragma unroll
  for (int r = 0; r < 4; r++) {
    float l = lR[r];
    l += __shfl_xor(l, 1);
    l += __shfl_xor(l, 2);
    l += __shfl_xor(l, 4);
    l += __shfl_xor(l, 8);
    float invl = 1.0f / l;
    u16* orow = aout + (size_t)(q0 + wave * 16 + quad * 4 + r) * 4096 + h * 256;
#pragma unroll
    for (int ni = 0; ni < 16; ni++)
      orow[ni * 16 + lane15] = f2bf(accO[ni][r] * invl);
  }
}

// ---------------------------------------------------------------------------
extern "C" void kernel_launch(void* const* d_in, const int* in_sizes, int n_in,
                              void* d_out, int out_size, void* d_ws, size_t ws_size,
                              hipStream_t stream)
{
  const void* hidden = d_in[0];
  const void* w_qkv  = d_in[1];
  const void* w_o    = d_in[2];
  const void* q_w    = d_in[3];
  const void* k_w    = d_in[4];
  const void* cosb   = d_in[5];
  const void* sinb   = d_in[6];

  char* ws = (char*)d_ws;
  int* flag = (int*)ws;                                   ws += 256;
  u16* qkv  = (u16*)ws;  ws += (size_t)2048 * 8192 * 2;
  u16* vT   = (u16*)ws;  ws += (size_t)8 * 256 * 2048 * 2;
  u16* aout = (u16*)ws;  ws += (size_t)2048 * 4096 * 2;
  u16* hb   = (u16*)ws;  ws += (size_t)2048 * 3584 * 2;
  u16* wT   = (u16*)ws;

  probe_dtype_kernel<<<1, 256, 0, stream>>>(hidden, flag);
  convert_dyn_kernel<<<3584, 256, 0, stream>>>(hidden, hb, (size_t)2048 * 3584, flag);
  transpose_dyn_kernel<<<dim3(128, 56), 256, 0, stream>>>(w_qkv, wT, 3584, 8192, flag);
  gemm_bt_kernel<<<dim3(64, 16), 256, 0, stream>>>(hb, wT, qkv, 2048, 8192, 3584, flag, 0);
  normrope_kernel<<<dim3(2048, 6), 256, 0, stream>>>(qkv, q_w, k_w, cosb, sinb, flag);
  transpose_dyn_kernel<<<dim3(56, 64), 256, 0, stream>>>(w_o, wT, 4096, 3584, flag);
  vtrans_kernel<<<dim3(32, 4, 8), 256, 0, stream>>>(qkv, vT);
  attn_kernel<<<dim3(32, 16), 256, 0, stream>>>(qkv, vT, aout);
  gemm_bt_kernel<<<dim3(28, 16), 256, 0, stream>>>(aout, wT, d_out, 2048, 3584, 4096, flag, 1);
}